// Round 2
// baseline (1295.171 us; speedup 1.0000x reference)
//
#include <hip/hip_runtime.h>

typedef _Float16 half8 __attribute__((ext_vector_type(8)));
typedef _Float16 half4 __attribute__((ext_vector_type(4)));
typedef float floatx4 __attribute__((ext_vector_type(4)));

#define B_  16
#define S_  2048
#define D_  256
#define BM  64
#define BN  32
#define NT  128
#define P_RS 40     // P strip row stride (f16): 80 B, 16B-multiple
#define OCH_RS 72   // epilogue f32 row stride: 288 B, 16B-multiple
#define LOG2E 1.4426950408889634f

// LDS layouts (all swizzled to make BOTH staging writes and frag reads bank-even):
//  kt[j][d]: f16, row = 256 wide, 16B-chunk c stored at c ^ (j&7)
//  vt[d][j]: f16, row = 32 wide,  8B-block e stored at e ^ (2*(d&3))
__global__ __launch_bounds__(NT, 2)
void attn_v2(const float* __restrict__ q, const float* __restrict__ k,
             const float* __restrict__ v, const int* __restrict__ mask,
             float* __restrict__ out)
{
    __shared__ __align__(16) char smem[BN*256*2 + 256*BN*2 + 2*32*P_RS*2 + BN*4];
    _Float16* kt   = (_Float16*)smem;            // [32][256] swizzled
    _Float16* vt   = kt + BN*256;                // [256][32] swizzled
    _Float16* pbuf = vt + 256*BN;                // [2 waves][32][P_RS]
    float*    moffs= (float*)(pbuf + 2*32*P_RS); // [32]
    float*    och  = (float*)smem;               // epilogue [64][OCH_RS] f32 (reuse)

    const int tid  = threadIdx.x;
    const int w    = tid >> 6;      // wave 0..1
    const int lane = tid & 63;
    const int n15  = lane & 15;
    const int qq   = lane >> 4;     // 0..3

    // XCD swizzle: each XCD owns 2 batches x 32 Q-tiles
    const int bx = blockIdx.x;
    const int x  = bx & 7;
    const int j_ = bx >> 3;         // 0..63
    const int b  = 2*x + (j_ >> 5);
    const int qt = j_ & 31;
    const int i0 = qt * BM;

    const float* qb = q + (size_t)b * S_ * D_;
    const float* kb = k + (size_t)b * D_ * S_;
    const float* vb = v + (size_t)b * S_ * D_;
    const int*   mb = mask + (size_t)b * S_;
    float*       ob = out + (size_t)b * D_ * S_;

    // ---- Q fragments: 2 strips of 16 rows per wave (rows i0+32w+16st+n15)
    half8 qf[2][8];
    #pragma unroll
    for (int st = 0; st < 2; ++st) {
        const float* qrow = qb + (size_t)(i0 + 32*w + 16*st + n15) * D_;
        #pragma unroll
        for (int s = 0; s < 8; ++s) {
            const float4 a = *(const float4*)(qrow + 32*s + 8*qq);
            const float4 c = *(const float4*)(qrow + 32*s + 8*qq + 4);
            half8 h;
            h[0]=(_Float16)a.x; h[1]=(_Float16)a.y; h[2]=(_Float16)a.z; h[3]=(_Float16)a.w;
            h[4]=(_Float16)c.x; h[5]=(_Float16)c.y; h[6]=(_Float16)c.z; h[7]=(_Float16)c.w;
            qf[st][s] = h;
        }
    }

    floatx4 o[2][16];
    #pragma unroll
    for (int st = 0; st < 2; ++st)
        #pragma unroll
        for (int ct = 0; ct < 16; ++ct) o[st][ct] = (floatx4){0.f,0.f,0.f,0.f};
    float m_r[2][4], l_r[2][4];
    #pragma unroll
    for (int st = 0; st < 2; ++st)
        #pragma unroll
        for (int r = 0; r < 4; ++r) { m_r[st][r] = -3.0e38f; l_r[st][r] = 0.f; }

    _Float16* pw = pbuf + w * 32 * P_RS;

    for (int t = 0; t < S_/BN; ++t) {
        const int j0 = t * BN;

        // ---- stage K: lane holds 8 consecutive d of one j -> packed b128 write
        #pragma unroll
        for (int r = 0; r < 8; ++r) {
            const int id = tid + NT*r;          // 0..1023
            const int j  = id & 31;
            const int c  = id >> 5;             // 16B chunk along d, 0..31
            const float* kp = kb + (size_t)(8*c) * S_ + j0 + j;
            half8 h;
            #pragma unroll
            for (int i2 = 0; i2 < 8; ++i2) h[i2] = (_Float16)kp[(size_t)i2 * S_];
            *(half8*)(kt + j*256 + 8*(c ^ (j & 7))) = h;
        }
        // ---- stage V: lane holds 4 consecutive j of one d -> packed b64 write
        #pragma unroll
        for (int r = 0; r < 16; ++r) {
            const int id = tid + NT*r;          // 0..2047
            const int d  = id & 255;
            const int jg = id >> 8;             // 0..7 (j-quad)
            const float* vp = vb + (size_t)(j0 + 4*jg) * D_ + d;
            half4 h;
            #pragma unroll
            for (int i2 = 0; i2 < 4; ++i2) h[i2] = (_Float16)vp[(size_t)i2 * D_];
            *(half4*)(vt + d*32 + 4*(jg ^ (2*(d & 3)))) = h;
        }
        if (tid < BN) moffs[tid] = mb[j0 + tid] ? 0.0f : -1.0e9f;
        __syncthreads();

        // ---- S = Q K (2 strips x 2 col-tiles; B-frag shared across strips)
        floatx4 sc[2][2];
        sc[0][0]=(floatx4){0,0,0,0}; sc[0][1]=(floatx4){0,0,0,0};
        sc[1][0]=(floatx4){0,0,0,0}; sc[1][1]=(floatx4){0,0,0,0};
        #pragma unroll
        for (int s = 0; s < 8; ++s) {
            #pragma unroll
            for (int ct = 0; ct < 2; ++ct) {
                const int jj = 16*ct + n15;
                const half8 kb8 = *(const half8*)(kt + jj*256 + 8*((4*s + qq) ^ (n15 & 7)));
                sc[0][ct] = __builtin_amdgcn_mfma_f32_16x16x32_f16(qf[0][s], kb8, sc[0][ct], 0,0,0);
                sc[1][ct] = __builtin_amdgcn_mfma_f32_16x16x32_f16(qf[1][s], kb8, sc[1][ct], 0,0,0);
            }
        }

        // ---- mask + online softmax per strip (C layout: row=4qq+r, col=16ct+n15)
        const float mo0 = moffs[n15], mo1 = moffs[16 + n15];
        float pv[2][2][4], alpha[2][4];
        bool need = false;
        #pragma unroll
        for (int st = 0; st < 2; ++st) {
            float sv0[4], sv1[4], mx[4];
            #pragma unroll
            for (int r = 0; r < 4; ++r) {
                sv0[r] = sc[st][0][r] + mo0;
                sv1[r] = sc[st][1][r] + mo1;
                mx[r]  = fmaxf(sv0[r], sv1[r]);
            }
            #pragma unroll
            for (int off = 1; off <= 8; off <<= 1)
                #pragma unroll
                for (int r = 0; r < 4; ++r) mx[r] = fmaxf(mx[r], __shfl_xor(mx[r], off, 64));
            float rs[4];
            #pragma unroll
            for (int r = 0; r < 4; ++r) {
                const float mn = fmaxf(m_r[st][r], mx[r]);
                alpha[st][r] = __builtin_amdgcn_exp2f((m_r[st][r] - mn) * LOG2E);
                m_r[st][r]   = mn;
                pv[st][0][r] = __builtin_amdgcn_exp2f((sv0[r] - mn) * LOG2E);
                pv[st][1][r] = __builtin_amdgcn_exp2f((sv1[r] - mn) * LOG2E);
                rs[r] = pv[st][0][r] + pv[st][1][r];
                need = need || (alpha[st][r] < 1.0f);
            }
            #pragma unroll
            for (int off = 1; off <= 8; off <<= 1)
                #pragma unroll
                for (int r = 0; r < 4; ++r) rs[r] += __shfl_xor(rs[r], off, 64);
            #pragma unroll
            for (int r = 0; r < 4; ++r) l_r[st][r] = l_r[st][r]*alpha[st][r] + rs[r];
        }

        // ---- P (C layout) -> per-wave LDS strip (A layout source)
        #pragma unroll
        for (int st = 0; st < 2; ++st)
            #pragma unroll
            for (int ct2 = 0; ct2 < 2; ++ct2)
                #pragma unroll
                for (int r = 0; r < 4; ++r)
                    pw[(16*st + 4*qq + r)*P_RS + 16*ct2 + n15] = (_Float16)pv[st][ct2][r];

        // rescale O only when some alpha < 1 (max actually moved)
        if (__any(need)) {
            #pragma unroll
            for (int st = 0; st < 2; ++st)
                #pragma unroll
                for (int ct = 0; ct < 16; ++ct)
                    #pragma unroll
                    for (int r = 0; r < 4; ++r) o[st][ct][r] *= alpha[st][r];
        }

        // same-wave cross-lane LDS hazard: drain P writes
        asm volatile("s_waitcnt lgkmcnt(0)" ::: "memory");
        const half8 pa0 = *(const half8*)(pw + (n15     )*P_RS + 8*qq);
        const half8 pa1 = *(const half8*)(pw + (16 + n15)*P_RS + 8*qq);
        #pragma unroll
        for (int ct = 0; ct < 16; ++ct) {
            const int dd = 16*ct + n15;
            const half8 vb8 = *(const half8*)(vt + dd*32 + 8*(qq ^ (n15 & 3)));
            o[0][ct] = __builtin_amdgcn_mfma_f32_16x16x32_f16(pa0, vb8, o[0][ct], 0,0,0);
            o[1][ct] = __builtin_amdgcn_mfma_f32_16x16x32_f16(pa1, vb8, o[1][ct], 0,0,0);
        }
        __syncthreads();
    }

    // ---- epilogue: out[b][d][i] = O[i][d]/(16*l_i), transposed via LDS (4 passes)
    float osc[2][4];
    #pragma unroll
    for (int st = 0; st < 2; ++st)
        #pragma unroll
        for (int r = 0; r < 4; ++r) osc[st][r] = 1.0f / (l_r[st][r] * 16.0f);

    #pragma unroll
    for (int p2 = 0; p2 < 4; ++p2) {        // 64 d-columns per pass
        #pragma unroll
        for (int c = 0; c < 4; ++c) {
            const int ct = 4*p2 + c;
            #pragma unroll
            for (int st = 0; st < 2; ++st)
                #pragma unroll
                for (int r = 0; r < 4; ++r)
                    och[(16*c + n15)*OCH_RS + 32*w + 16*st + 4*qq + r] = o[st][ct][r] * osc[st][r];
        }
        __syncthreads();
        #pragma unroll
        for (int it = 0; it < 8; ++it) {
            const int dl = 8*it + (tid >> 4);
            const int fi = (tid & 15) * 4;
            const float4 vv = *(const float4*)(och + dl*OCH_RS + fi);
            *(float4*)(ob + (size_t)(64*p2 + dl)*S_ + i0 + fi) = vv;
        }
        __syncthreads();
    }
}

extern "C" void kernel_launch(void* const* d_in, const int* in_sizes, int n_in,
                              void* d_out, int out_size, void* d_ws, size_t ws_size,
                              hipStream_t stream)
{
    const float* q    = (const float*)d_in[0];
    const float* k    = (const float*)d_in[1];
    const float* v    = (const float*)d_in[2];
    const int*   mask = (const int*)d_in[3];
    float*       out  = (float*)d_out;
    attn_v2<<<dim3(B_ * (S_/BM)), dim3(NT), 0, stream>>>(q, k, v, mask, out);
}

// Round 3
// 440.225 us; speedup vs baseline: 2.9421x; 2.9421x over previous
//
#include <hip/hip_runtime.h>

typedef _Float16 half8 __attribute__((ext_vector_type(8)));
typedef float floatx16 __attribute__((ext_vector_type(16)));

#define B_  16
#define S_  2048
#define D_  256
#define P_RS 40
#define LOG2E 1.4426950408889634f

#define DPP_ROR(x, n) __int_as_float(__builtin_amdgcn_update_dpp( \
    0, __float_as_int(x), 0x120 + (n), 0xf, 0xf, false))

__device__ __forceinline__ float rmax32(float x) {
    x = fmaxf(x, DPP_ROR(x, 1));
    x = fmaxf(x, DPP_ROR(x, 2));
    x = fmaxf(x, DPP_ROR(x, 4));
    x = fmaxf(x, DPP_ROR(x, 8));
    x = fmaxf(x, __shfl_xor(x, 16, 64));
    return x;
}
__device__ __forceinline__ float rsum32(float x) {
    x += DPP_ROR(x, 1);
    x += DPP_ROR(x, 2);
    x += DPP_ROR(x, 4);
    x += DPP_ROR(x, 8);
    x += __shfl_xor(x, 16, 64);
    return x;
}

// ---- pre-pass: out[b][c][r] (f16) = in[b][r][c] (f32); 64x64 tiles ----
__global__ __launch_bounds__(256)
void tr_f32_f16(const float* __restrict__ in, _Float16* __restrict__ out,
                int R, int C)
{
    __shared__ float tile[64][65];
    const int t  = threadIdx.x;
    const int c0 = blockIdx.x * 64, r0 = blockIdx.y * 64;
    const float* ib = in  + (size_t)blockIdx.z * R * C;
    _Float16*    ob = out + (size_t)blockIdx.z * R * C;

    const int tr = t >> 4, tc = (t & 15) * 4;
    #pragma unroll
    for (int p = 0; p < 4; ++p) {
        const float4 x = *(const float4*)(ib + (size_t)(r0 + tr + 16*p) * C + c0 + tc);
        tile[tr + 16*p][tc + 0] = x.x;
        tile[tr + 16*p][tc + 1] = x.y;
        tile[tr + 16*p][tc + 2] = x.z;
        tile[tr + 16*p][tc + 3] = x.w;
    }
    __syncthreads();
    const int cl = t >> 2, rch = t & 3;
    half8 h0, h1;
    #pragma unroll
    for (int m = 0; m < 8; ++m) h0[m] = (_Float16)tile[16*rch + m][cl];
    #pragma unroll
    for (int m = 0; m < 8; ++m) h1[m] = (_Float16)tile[16*rch + 8 + m][cl];
    _Float16* op = ob + (size_t)(c0 + cl) * R + r0 + 16*rch;
    *(half8*)op       = h0;
    *(half8*)(op + 8) = h1;
}

// ---- main: barrier-free flash attention, 32x32x16 f16 MFMA ----
__global__ __launch_bounds__(256, 1)
void attn_v3(const float* __restrict__ q, const _Float16* __restrict__ kt,
             const _Float16* __restrict__ vt, const int* __restrict__ mask,
             float* __restrict__ out)
{
    __shared__ float    moffs[S_];
    __shared__ _Float16 pbuf[4][32 * P_RS];

    const int tid  = threadIdx.x;
    const int w    = tid >> 6;
    const int lane = tid & 63;
    const int jl   = lane & 31;
    const int h    = lane >> 5;

    // XCD swizzle: each XCD owns all 16 Q-tiles of 2 batches
    const int bx = blockIdx.x;
    const int x  = bx & 7;
    const int j_ = bx >> 3;
    const int b  = 2*x + (j_ >> 4);
    const int qt = j_ & 15;
    const int i0 = qt * 128;
    const int iw = i0 + 32 * w;          // this wave's 32-row strip

    const float*    qb  = q  + (size_t)b * S_ * D_;
    const _Float16* ktb = kt + (size_t)b * S_ * D_;   // [S][D]
    const _Float16* vtb = vt + (size_t)b * S_ * D_;   // [D][S]
    const int*      mb  = mask + (size_t)b * S_;
    float*          ob  = out + (size_t)b * D_ * S_;

    for (int i = tid; i < S_; i += 256) moffs[i] = mb[i] ? 0.0f : -1.0e9f;

    // Q A-frags: A[m=iw+jl][k=16s+8h+0..7], f16 in regs
    half8 qf[16];
    {
        const float* qrow = qb + (size_t)(iw + jl) * D_;
        #pragma unroll
        for (int s = 0; s < 16; ++s) {
            const float4 a = *(const float4*)(qrow + 16*s + 8*h);
            const float4 c = *(const float4*)(qrow + 16*s + 8*h + 4);
            half8 v;
            v[0]=(_Float16)a.x; v[1]=(_Float16)a.y; v[2]=(_Float16)a.z; v[3]=(_Float16)a.w;
            v[4]=(_Float16)c.x; v[5]=(_Float16)c.y; v[6]=(_Float16)c.z; v[7]=(_Float16)c.w;
            qf[s] = v;
        }
    }
    __syncthreads();   // moffs ready; only barrier with memory semantics

    floatx16 o[8];
    #pragma unroll
    for (int nt = 0; nt < 8; ++nt) o[nt] = (floatx16){};
    float M[16], lsum[16];
    #pragma unroll
    for (int r = 0; r < 16; ++r) { M[r] = -1.0e30f; lsum[r] = 0.0f; }

    _Float16* pw = pbuf[w];

    for (int t = 0; t < S_/32; ++t) {
        const int j0 = 32 * t;

        // hoisted global fragment loads (all independent -> deep MLP)
        half8 kf[16];
        #pragma unroll
        for (int s = 0; s < 16; ++s)
            kf[s] = *(const half8*)(ktb + (size_t)(j0 + jl) * D_ + 16*s + 8*h);
        half8 vf0[8], vf1[8];
        #pragma unroll
        for (int nt = 0; nt < 8; ++nt) {
            const _Float16* vr = vtb + (size_t)(32*nt + jl) * S_ + j0;
            vf0[nt] = *(const half8*)(vr + 8*h);
            vf1[nt] = *(const half8*)(vr + 16 + 8*h);
        }
        const float mo = moffs[j0 + jl];

        // pacing only: keep the 4 waves' tile phases aligned for L1 reuse.
        // No memory semantics needed (each wave consumes only its own loads).
        asm volatile("s_barrier");

        // S = Q K^T : two independent accumulation chains
        floatx16 sa = (floatx16){}, sb = (floatx16){};
        #pragma unroll
        for (int s2 = 0; s2 < 8; ++s2) {
            sa = __builtin_amdgcn_mfma_f32_32x32x16_f16(qf[2*s2],   kf[2*s2],   sa, 0,0,0);
            sb = __builtin_amdgcn_mfma_f32_32x32x16_f16(qf[2*s2+1], kf[2*s2+1], sb, 0,0,0);
        }

        // C layout: col j = jl, row i = (r&3) + 8*(r>>2) + 4h
        float sv[16];
        #pragma unroll
        for (int r = 0; r < 16; ++r) sv[r] = sa[r] + sb[r] + mo;

        // exact per-row max via DPP (VALU pipe) + 1 swizzle
        float Mn[16];
        bool up = false;
        #pragma unroll
        for (int r = 0; r < 16; ++r) {
            const float tm = rmax32(sv[r]);
            Mn[r] = fmaxf(M[r], tm);
            up = up || (Mn[r] > M[r]);
        }
        if (__any(up)) {
            #pragma unroll
            for (int r = 0; r < 16; ++r) {
                const float al = __builtin_amdgcn_exp2f((M[r] - Mn[r]) * LOG2E);
                M[r] = Mn[r];
                lsum[r] *= al;
                #pragma unroll
                for (int nt = 0; nt < 8; ++nt) o[nt][r] *= al;
            }
        }

        _Float16 ph[16];
        #pragma unroll
        for (int r = 0; r < 16; ++r) {
            const float p = __builtin_amdgcn_exp2f((sv[r] - M[r]) * LOG2E);
            lsum[r] += p;               // deferred j-reduction (per-lane partial)
            ph[r] = (_Float16)p;
        }

        // P: C layout -> A layout via per-wave LDS strip (stride 40 f16: 2-way max)
        #pragma unroll
        for (int r = 0; r < 16; ++r)
            pw[((r&3) + 8*(r>>2) + 4*h) * P_RS + jl] = ph[r];
        asm volatile("s_waitcnt lgkmcnt(0)" ::: "memory");
        const half8 pa0 = *(const half8*)(pw + jl * P_RS + 8*h);
        const half8 pa1 = *(const half8*)(pw + jl * P_RS + 16 + 8*h);

        #pragma unroll
        for (int nt = 0; nt < 8; ++nt) {
            o[nt] = __builtin_amdgcn_mfma_f32_32x32x16_f16(pa0, vf0[nt], o[nt], 0,0,0);
            o[nt] = __builtin_amdgcn_mfma_f32_32x32x16_f16(pa1, vf1[nt], o[nt], 0,0,0);
        }
    }

    // epilogue: finish deferred row sums, scale, store out[b][d][i]
    float osc[16];
    #pragma unroll
    for (int r = 0; r < 16; ++r) {
        const float L = rsum32(lsum[r]);
        osc[r] = 1.0f / (16.0f * L);
    }
    #pragma unroll
    for (int nt = 0; nt < 8; ++nt) {
        float* od = ob + (size_t)(32*nt + jl) * S_ + iw;
        #pragma unroll
        for (int r = 0; r < 16; ++r)
            od[(r&3) + 8*(r>>2) + 4*h] = o[nt][r] * osc[r];
    }
}

extern "C" void kernel_launch(void* const* d_in, const int* in_sizes, int n_in,
                              void* d_out, int out_size, void* d_ws, size_t ws_size,
                              hipStream_t stream)
{
    const float* q    = (const float*)d_in[0];
    const float* k    = (const float*)d_in[1];   // [B][D][S]
    const float* v    = (const float*)d_in[2];   // [B][S][D]
    const int*   mask = (const int*)d_in[3];
    float*       out  = (float*)d_out;

    _Float16* kt = (_Float16*)d_ws;                       // [B][S][D]
    _Float16* vt = kt + (size_t)B_ * S_ * D_;             // [B][D][S]

    // K: in [256][2048] -> out [2048][256]
    tr_f32_f16<<<dim3(S_/64, D_/64, B_), dim3(256), 0, stream>>>(k, kt, D_, S_);
    // V: in [2048][256] -> out [256][2048]
    tr_f32_f16<<<dim3(D_/64, S_/64, B_), dim3(256), 0, stream>>>(v, vt, S_, D_);

    attn_v3<<<dim3(B_ * (S_/128)), dim3(256), 0, stream>>>(q, kt, vt, mask, out);
}

// Round 4
// 333.037 us; speedup vs baseline: 3.8890x; 1.3218x over previous
//
#include <hip/hip_runtime.h>

typedef _Float16 half8 __attribute__((ext_vector_type(8)));
typedef float floatx16 __attribute__((ext_vector_type(16)));

#define B_  16
#define S_  2048
#define D_  256
#define P_RS 40
#define LOG2E 1.4426950408889634f

#define DPP_ROR(x, n) __int_as_float(__builtin_amdgcn_update_dpp( \
    0, __float_as_int(x), 0x120 + (n), 0xf, 0xf, false))

__device__ __forceinline__ float rmax32(float x) {
    x = fmaxf(x, DPP_ROR(x, 1));
    x = fmaxf(x, DPP_ROR(x, 2));
    x = fmaxf(x, DPP_ROR(x, 4));
    x = fmaxf(x, DPP_ROR(x, 8));
    x = fmaxf(x, __shfl_xor(x, 16, 64));
    return x;
}
__device__ __forceinline__ float rsum32(float x) {
    x += DPP_ROR(x, 1);
    x += DPP_ROR(x, 2);
    x += DPP_ROR(x, 4);
    x += DPP_ROR(x, 8);
    x += __shfl_xor(x, 16, 64);
    return x;
}

// async 16B/lane global -> LDS DMA; lds base wave-uniform, HW adds lane*16
__device__ __forceinline__ void dma16(const _Float16* g, _Float16* l) {
    __builtin_amdgcn_global_load_lds(
        (const __attribute__((address_space(1))) void*)g,
        (__attribute__((address_space(3))) void*)l, 16, 0, 0);
}

// out[c][r] (f16) = in[r][c] (f32). If swz: 16B-chunk c' = (c&~7)|((c&7)^((row>>1)&7))
// so the main kernel's LDS-resident K rows have bank-even fragment reads.
__global__ __launch_bounds__(256)
void tr_swz(const float* __restrict__ in, _Float16* __restrict__ out,
            int Rin, int Cin, int swz)
{
    __shared__ _Float16 tl[64 * 72];
    const int t  = threadIdx.x;
    const int c0 = blockIdx.x * 64, r0 = blockIdx.y * 64;
    const float* ib = in  + (size_t)blockIdx.z * Rin * Cin;
    _Float16*    ob = out + (size_t)blockIdx.z * Rin * Cin;

    const int rr = t >> 4, cc = (t & 15) * 4;
    #pragma unroll
    for (int p = 0; p < 4; ++p) {
        const float4 x = *(const float4*)(ib + (size_t)(r0 + rr + 16*p) * Cin + c0 + cc);
        tl[(cc+0)*72 + rr + 16*p] = (_Float16)x.x;
        tl[(cc+1)*72 + rr + 16*p] = (_Float16)x.y;
        tl[(cc+2)*72 + rr + 16*p] = (_Float16)x.z;
        tl[(cc+3)*72 + rr + 16*p] = (_Float16)x.w;
    }
    __syncthreads();
    #pragma unroll
    for (int u = 0; u < 2; ++u) {
        const int idx  = t + 256*u;
        const int jloc = idx >> 3, lc = idx & 7;
        const half8 h = *(const half8*)(tl + jloc*72 + 8*lc);
        const int jg  = c0 + jloc;
        const int lco = swz ? (lc ^ ((jg >> 1) & 7)) : lc;
        *(half8*)(ob + (size_t)jg * Rin + r0 + 8*lco) = h;
    }
}

__global__ __launch_bounds__(128, 1)
void attn_v4(const float* __restrict__ q, const _Float16* __restrict__ kts,
             const _Float16* __restrict__ vt, const int* __restrict__ mask,
             float* __restrict__ out)
{
    __shared__ _Float16 kb[2][32 * D_];      // K tile dbuf (swizzled rows)
    __shared__ _Float16 pbuf[2][32 * P_RS];  // per-wave P strips

    const int tid  = threadIdx.x;
    const int w    = tid >> 6;
    const int lane = tid & 63;
    const int jl   = lane & 31;
    const int h    = lane >> 5;
    const int pj   = (jl >> 1) & 7;

    // XCD swizzle: each XCD owns 2 batches x 32 row-groups
    const int bx   = blockIdx.x;
    const int rest = bx >> 3;
    const int b    = 2 * (bx & 7) + (rest >> 5);
    const int qg   = rest & 31;
    const int i0   = qg * 64 + 32 * w;       // this wave's 32-row strip

    const float*    qb  = q    + (size_t)b * S_ * D_;
    const _Float16* ktb = kts  + (size_t)b * S_ * D_;   // [S][D] swizzled
    const _Float16* vtb = vt   + (size_t)b * S_ * D_;   // [D][S]
    const int*      mb  = mask + (size_t)b * S_;
    float*          ob  = out  + (size_t)b * D_ * S_;

    // Q A-frags: A[m=i0+jl][k=16s+8h+0..7]
    half8 qf[16];
    {
        const float* qrow = qb + (size_t)(i0 + jl) * D_;
        #pragma unroll
        for (int s = 0; s < 16; ++s) {
            const float4 a = *(const float4*)(qrow + 16*s + 8*h);
            const float4 c = *(const float4*)(qrow + 16*s + 8*h + 4);
            half8 v;
            v[0]=(_Float16)a.x; v[1]=(_Float16)a.y; v[2]=(_Float16)a.z; v[3]=(_Float16)a.w;
            v[4]=(_Float16)c.x; v[5]=(_Float16)c.y; v[6]=(_Float16)c.z; v[7]=(_Float16)c.w;
            qf[s] = v;
        }
    }

    floatx16 o[8];
    #pragma unroll
    for (int nt = 0; nt < 8; ++nt) o[nt] = (floatx16){};
    float M[16], pc[16], lsum[16];
    #pragma unroll
    for (int r = 0; r < 16; ++r) { M[r] = -3.0e38f; pc[r] = 0.0f; lsum[r] = 0.0f; }

    _Float16* pw = pbuf[w];

    // preload K tile 0 (wave w stages rows 16w..16w+15; 2 rows per DMA instr)
    #pragma unroll
    for (int m = 0; m < 8; ++m)
        dma16(ktb + (size_t)(16*w + 2*m) * D_ + lane*8, kb[0] + (16*w + 2*m) * D_);
    __syncthreads();

    for (int t = 0; t < S_/32; ++t) {
        const int j0 = 32 * t;
        const int jn = ((t + 1) & 63) * 32;      // wraps harmlessly on last iter
        const _Float16* kcur = kb[t & 1];
        _Float16*       knxt = kb[(t + 1) & 1];

        // prefetch next K tile via async DMA (landed by iter-end barrier)
        #pragma unroll
        for (int m = 0; m < 8; ++m)
            dma16(ktb + (size_t)(jn + 16*w + 2*m) * D_ + lane*8,
                  knxt + (16*w + 2*m) * D_);

        // hoist V frags (B[n=32nt+jl][k=16ks+8h+..]) + mask; used ~800 cyc later
        half8 vf0[8], vf1[8];
        #pragma unroll
        for (int nt = 0; nt < 8; ++nt) {
            const _Float16* vr = vtb + (size_t)(32*nt + jl) * S_ + j0 + 8*h;
            vf0[nt] = *(const half8*)(vr);
            vf1[nt] = *(const half8*)(vr + 16);
        }
        const float mo = mb[j0 + jl] ? 0.0f : -1.0e9f;

        // S = Q K^T from LDS (swizzled chunks), two accumulation chains
        floatx16 sa = (floatx16){}, sb = (floatx16){};
        #pragma unroll
        for (int s = 0; s < 16; s += 2) {
            const half8 k0 = *(const half8*)(kcur + jl*D_ + 8*((2*s     + h) ^ pj));
            const half8 k1 = *(const half8*)(kcur + jl*D_ + 8*((2*s + 2 + h) ^ pj));
            sa = __builtin_amdgcn_mfma_f32_32x32x16_f16(qf[s],   k0, sa, 0,0,0);
            sb = __builtin_amdgcn_mfma_f32_32x32x16_f16(qf[s+1], k1, sb, 0,0,0);
        }
        float sv[16];
        #pragma unroll
        for (int r = 0; r < 16; ++r) sv[r] = sa[r] + sb[r] + mo;

        // lazy online max: only rescale when some row exceeds reference M by >8
        float mx = sv[0] - M[0];
        #pragma unroll
        for (int r = 1; r < 16; ++r) mx = fmaxf(mx, sv[r] - M[r]);
        if (__any(mx > 8.0f)) {
            #pragma unroll
            for (int r = 0; r < 16; ++r) {
                const float tm = rmax32(sv[r]);
                const float Mn = fmaxf(M[r], tm);
                const float al = __builtin_amdgcn_exp2f((M[r] - Mn) * LOG2E);
                M[r] = Mn; pc[r] = -Mn * LOG2E;
                lsum[r] *= al;
                #pragma unroll
                for (int nt = 0; nt < 8; ++nt) o[nt][r] *= al;
            }
        }

        // p = e^(sv-M) (<= e^8, f16-safe); deferred per-lane row sums
        #pragma unroll
        for (int r = 0; r < 16; ++r) {
            const float p = __builtin_amdgcn_exp2f(fmaf(sv[r], LOG2E, pc[r]));
            lsum[r] += p;
            pw[((r&3) + 8*(r>>2) + 4*h) * P_RS + jl] = (_Float16)p;
        }
        asm volatile("s_waitcnt lgkmcnt(0)" ::: "memory");
        const half8 pa0 = *(const half8*)(pw + jl*P_RS + 8*h);
        const half8 pa1 = *(const half8*)(pw + jl*P_RS + 16 + 8*h);

        #pragma unroll
        for (int nt = 0; nt < 8; ++nt) {
            o[nt] = __builtin_amdgcn_mfma_f32_32x32x16_f16(pa0, vf0[nt], o[nt], 0,0,0);
            o[nt] = __builtin_amdgcn_mfma_f32_32x32x16_f16(pa1, vf1[nt], o[nt], 0,0,0);
        }

        // drains K(t+1) DMA + protects kcur from next iter's DMA overwrite
        __syncthreads();
    }

    // epilogue: finish row sums, scale by 1/(16 l), store out[b][d][i]
    float osc[16];
    #pragma unroll
    for (int r = 0; r < 16; ++r) osc[r] = 1.0f / (16.0f * rsum32(lsum[r]));
    #pragma unroll
    for (int nt = 0; nt < 8; ++nt) {
        float* od = ob + (size_t)(32*nt + jl) * S_ + i0;
        #pragma unroll
        for (int r = 0; r < 16; ++r)
            od[(r&3) + 8*(r>>2) + 4*h] = o[nt][r] * osc[r];
    }
}

extern "C" void kernel_launch(void* const* d_in, const int* in_sizes, int n_in,
                              void* d_out, int out_size, void* d_ws, size_t ws_size,
                              hipStream_t stream)
{
    const float* q    = (const float*)d_in[0];
    const float* k    = (const float*)d_in[1];   // [B][D][S]
    const float* v    = (const float*)d_in[2];   // [B][S][D]
    const int*   mask = (const int*)d_in[3];
    float*       out  = (float*)d_out;

    _Float16* kt = (_Float16*)d_ws;               // [B][S][D] swizzled
    _Float16* vtp = kt + (size_t)B_ * S_ * D_;    // [B][D][S]

    // K: [256][2048] -> swizzled [2048][256]
    tr_swz<<<dim3(S_/64, D_/64, B_), dim3(256), 0, stream>>>(k, kt, D_, S_, 1);
    // V: [2048][256] -> [256][2048]
    tr_swz<<<dim3(D_/64, S_/64, B_), dim3(256), 0, stream>>>(v, vtp, S_, D_, 0);

    attn_v4<<<dim3(B_ * (S_/64)), dim3(128), 0, stream>>>(q, kt, vtp, mask, out);
}